// Round 7
// baseline (68.843 us; speedup 1.0000x reference)
//
#include <hip/hip_runtime.h>
#include <math.h>

// Problem constants (match reference)
#define S 64
#define NC 64          // channels (C=64 -> one NHWC bf16 pixel = 128B contiguous)
#define HF 128
#define WF 128
#define HW (HF * WF)   // 16384
#define SS (S * S)     // 4096, channel stride in out
#define ROWS 4         // rows per block (double-buffered LDS pipeline)
#define EXPANDF 1.25f
#define FEAT_DOWN_INV 0.125f
#define DEG2RADF 0.017453292519943295f

__device__ __forceinline__ unsigned int f32_to_bf16_rne(float v) {
    unsigned int u = __float_as_uint(v);
    return (u + 0x7FFFu + ((u >> 16) & 1u)) >> 16;   // finite data: no NaN concern
}
__device__ __forceinline__ float bf16_bits_to_f32(unsigned int h) {
    return __uint_as_float(h << 16);
}

// ---- NCHW f32 -> NHWC bf16 transpose, LDS-tiled (both sides coalesced) ----
__global__ __launch_bounds__(256) void nchw_to_nhwc_bf16_kernel(
    const float*    __restrict__ feat,    // (B, C, HF, WF) f32
    unsigned short* __restrict__ featT)   // (B, HF, WF, C) bf16
{
    __shared__ float lds[64 * 65];
    const int bh  = blockIdx.x;           // b*HF + h
    const int b   = bh >> 7;
    const int h   = bh & (HF - 1);
    const int w0  = blockIdx.y << 6;      // 64-wide w tile
    const int tid = threadIdx.x;
    const int t4  = tid >> 6;             // 0..3
    const int t64 = tid & 63;

#pragma unroll
    for (int k = 0; k < 16; ++k) {        // read: lanes contiguous in w (256B)
        const int c = (k << 2) + t4;
        lds[t64 * 65 + c] = feat[(((size_t)b * NC + c) * HF + h) * WF + w0 + t64];
    }
    __syncthreads();
#pragma unroll
    for (int k = 0; k < 16; ++k) {        // write: lanes contiguous in c (128B)
        const int w = (k << 2) + t4;
        featT[(((size_t)b * HF + h) * WF + w0 + w) * NC + t64] =
            (unsigned short)f32_to_bf16_rne(lds[w * 65 + t64]);
    }
}

// ---- main: channel-in-lanes bf16 gather + LDS transpose, row-pipelined ----
// block = ROWS (n, i) output rows; double-buffered LDS overlaps store(r-1) with gather(r).
__global__ __launch_bounds__(256, 4) void RotatedROIPool_kernel(
    const unsigned short* __restrict__ featT,  // (B, HF, WF, C) bf16
    const float*          __restrict__ obb,    // (N, 5)
    const int*            __restrict__ bix,    // (N,)
    float*                __restrict__ out,    // (N, C, S, S)
    int nwg_per_xcd)
{
    __shared__ float lds[2][64 * 65];   // [buf][sample j][channel c], +1 pad (0-conflict, R4/R5)

    // bijective XCD swizzle: consecutive row-groups of one ROI stay on one XCD (L2 reuse)
    const int bid = blockIdx.x;
    const int wg  = (bid & 7) * nwg_per_xcd + (bid >> 3);
    const int n   = wg >> 4;            // ROI
    const int i0  = (wg & 15) << 2;     // row base (ROWS=4)

    const int tid  = threadIdx.x;
    const int wv   = tid >> 6;          // wave 0..3
    const int lane = tid & 63;
    const int s    = lane >> 3;         // sample-within-group 0..7
    const int c8   = lane & 7;          // channel group (8 bf16 = 16B each)
    const int jg   = tid & 15;          // phase-2 j group
    const int cl   = tid >> 4;          // phase-2 channel lane 0..15

    // --- per-ROI affine (once per block) ---
    const float o0 = obb[n * 5 + 0];
    const float o1 = obb[n * 5 + 1];
    const float o2 = obb[n * 5 + 2];
    const float o3 = obb[n * 5 + 3];
    const float o4 = obb[n * 5 + 4];

    const float cx  = o0 * FEAT_DOWN_INV;
    const float cy  = o1 * FEAT_DOWN_INV;
    const float wsc = o2 * FEAT_DOWN_INV * EXPANDF;
    const float hsc = o3 * FEAT_DOWN_INV * EXPANDF;
    const float th  = o4 * DEG2RADF;

    float sth, cth;
    sincosf(th, &sth, &cth);

    const float sx  = wsc * (1.0f / (float)S);
    const float sy  = hsc * (1.0f / (float)S);
    const float m00 = cth * sx;
    const float m01 = -sth * sy;
    const float m10 = EXPANDF * sx;     // replicate reference exactly (diagonal quirk)
    const float m11 = cth * sy;

    const int b = bix[n];
    const unsigned char* __restrict__ pb =
        (const unsigned char*)featT + (size_t)b * ((size_t)HW * NC * 2);

    float* __restrict__ obase = out + (size_t)n * NC * SS;

#pragma unroll
    for (int r = 0; r < ROWS; ++r) {
        const int i = i0 + r;
        const float yg = (2.0f * (float)i + 1.0f) * (1.0f / (float)S) - 1.0f;
        const float hx = m01 * yg + cx;
        const float hy = m11 * yg + cy;

        // --- compute weights/addresses and ISSUE all 8 gather loads first ---
        uint4  a00[2], a01[2], a10[2], a11[2];
        float  w00[2], w01[2], w10[2], w11[2];
#pragma unroll
        for (int sg = 0; sg < 2; ++sg) {
            const int j = (wv << 4) + (sg << 3) + s;

            const float xg = (2.0f * (float)j + 1.0f) * (1.0f / (float)S) - 1.0f;
            const float gx = m00 * xg + hx;
            const float gy = m10 * xg + hy;

            const float ix = ((gx + 1.0f) * (float)WF - 1.0f) * 0.5f;
            const float iy = ((gy + 1.0f) * (float)HF - 1.0f) * 0.5f;

            const float x0f = floorf(ix);
            const float y0f = floorf(iy);
            const float wx1 = ix - x0f;
            const float wy1 = iy - y0f;
            const float wx0 = 1.0f - wx1;
            const float wy0 = 1.0f - wy1;

            const int x0 = (int)x0f;
            const int y0 = (int)y0f;
            const int x1 = x0 + 1;
            const int y1 = y0 + 1;

            const float vx0 = (x0 >= 0 && x0 < WF) ? 1.0f : 0.0f;
            const float vx1 = (x1 >= 0 && x1 < WF) ? 1.0f : 0.0f;
            const float vy0 = (y0 >= 0 && y0 < HF) ? 1.0f : 0.0f;
            const float vy1 = (y1 >= 0 && y1 < HF) ? 1.0f : 0.0f;

            w00[sg] = wy0 * wx0 * vy0 * vx0;
            w01[sg] = wy0 * wx1 * vy0 * vx1;
            w10[sg] = wy1 * wx0 * vy1 * vx0;
            w11[sg] = wy1 * wx1 * vy1 * vx1;

            const int x0c = min(max(x0, 0), WF - 1);
            const int x1c = min(max(x1, 0), WF - 1);
            const int y0c = min(max(y0, 0), HF - 1);
            const int y1c = min(max(y1, 0), HF - 1);

            // bf16 pixel = 128B; lane adds c8*16B -> each instr covers 8 pixels, lines full
            a00[sg] = *((const uint4*)(pb + ((size_t)(y0c * WF + x0c) << 7)) + c8);
            a01[sg] = *((const uint4*)(pb + ((size_t)(y0c * WF + x1c) << 7)) + c8);
            a10[sg] = *((const uint4*)(pb + ((size_t)(y1c * WF + x0c) << 7)) + c8);
            a11[sg] = *((const uint4*)(pb + ((size_t)(y1c * WF + x1c) << 7)) + c8);
        }

        // --- overlap: store row r-1 from the other buffer while loads are in flight ---
        if (r > 0) {
            const float* __restrict__ Lp = lds[(r - 1) & 1];
            float* __restrict__ ob = obase + (size_t)(i - 1) * S;
#pragma unroll
            for (int k = 0; k < 4; ++k) {
                const int c = (k << 4) + cl;
                float4 t;
                t.x = Lp[(jg * 4 + 0) * 65 + c];
                t.y = Lp[(jg * 4 + 1) * 65 + c];
                t.z = Lp[(jg * 4 + 2) * 65 + c];
                t.w = Lp[(jg * 4 + 3) * 65 + c];
                *(float4*)(ob + (size_t)c * SS + (jg << 2)) = t;
            }
        }

        // --- consume gathers: unpack bf16, weight, write LDS[r&1] ---
        float* __restrict__ Lc = lds[r & 1];
#pragma unroll
        for (int sg = 0; sg < 2; ++sg) {
            const int j = (wv << 4) + (sg << 3) + s;
            const unsigned int* u00 = (const unsigned int*)&a00[sg];
            const unsigned int* u01 = (const unsigned int*)&a01[sg];
            const unsigned int* u10 = (const unsigned int*)&a10[sg];
            const unsigned int* u11 = (const unsigned int*)&a11[sg];
            float* L = Lc + j * 65 + (c8 << 3);
#pragma unroll
            for (int m = 0; m < 4; ++m) {
                const float f00l = bf16_bits_to_f32(u00[m] & 0xFFFFu);
                const float f01l = bf16_bits_to_f32(u01[m] & 0xFFFFu);
                const float f10l = bf16_bits_to_f32(u10[m] & 0xFFFFu);
                const float f11l = bf16_bits_to_f32(u11[m] & 0xFFFFu);
                const float f00h = bf16_bits_to_f32(u00[m] >> 16);
                const float f01h = bf16_bits_to_f32(u01[m] >> 16);
                const float f10h = bf16_bits_to_f32(u10[m] >> 16);
                const float f11h = bf16_bits_to_f32(u11[m] >> 16);
                L[2 * m + 0] = w00[sg] * f00l + w01[sg] * f01l + w10[sg] * f10l + w11[sg] * f11l;
                L[2 * m + 1] = w00[sg] * f00h + w01[sg] * f01h + w10[sg] * f10h + w11[sg] * f11h;
            }
        }

        __syncthreads();
    }

    // --- epilogue: store last row ---
    {
        const float* __restrict__ Lp = lds[(ROWS - 1) & 1];
        float* __restrict__ ob = obase + (size_t)(i0 + ROWS - 1) * S;
#pragma unroll
        for (int k = 0; k < 4; ++k) {
            const int c = (k << 4) + cl;
            float4 t;
            t.x = Lp[(jg * 4 + 0) * 65 + c];
            t.y = Lp[(jg * 4 + 1) * 65 + c];
            t.z = Lp[(jg * 4 + 2) * 65 + c];
            t.w = Lp[(jg * 4 + 3) * 65 + c];
            *(float4*)(ob + (size_t)c * SS + (jg << 2)) = t;
        }
    }
}

// ---- fallback (ws too small): NCHW f32 direct gather, CT=8 ----
__global__ __launch_bounds__(256) void RotatedROIPool_nchw_kernel(
    const float* __restrict__ feat, const float* __restrict__ obb,
    const int* __restrict__ bix, float* __restrict__ out)
{
    const int tid = threadIdx.x, pid = blockIdx.x;
    const int n = pid >> 4, patch = pid & 15;
    const int pi = (patch >> 2) << 4, pj = (patch & 3) << 4;
    const int w = tid >> 6, lane = tid & 63;
    const int i = pi + ((w >> 1) << 3) + (lane >> 3);
    const int j = pj + ((w & 1) << 3) + (lane & 7);
    const int c0 = blockIdx.y * 8;

    const float cx = obb[n*5+0]*FEAT_DOWN_INV, cy = obb[n*5+1]*FEAT_DOWN_INV;
    const float wsc = obb[n*5+2]*FEAT_DOWN_INV*EXPANDF, hsc = obb[n*5+3]*FEAT_DOWN_INV*EXPANDF;
    float sth, cth; sincosf(obb[n*5+4]*DEG2RADF, &sth, &cth);
    const float sx = wsc/(float)S, sy = hsc/(float)S;
    const float m00 = cth*sx, m01 = -sth*sy, m10 = EXPANDF*sx, m11 = cth*sy;
    const float xg = (2.f*j+1.f)/(float)S - 1.f, yg = (2.f*i+1.f)/(float)S - 1.f;
    const float gx = m00*xg + m01*yg + cx, gy = m10*xg + m11*yg + cy;
    const float ix = ((gx+1.f)*WF-1.f)*.5f, iy = ((gy+1.f)*HF-1.f)*.5f;
    const float x0f = floorf(ix), y0f = floorf(iy);
    const float wx1 = ix-x0f, wy1 = iy-y0f, wx0 = 1.f-wx1, wy0 = 1.f-wy1;
    const int x0 = (int)x0f, y0 = (int)y0f, x1 = x0+1, y1 = y0+1;
    const float vx0 = (x0>=0&&x0<WF)?1.f:0.f, vx1 = (x1>=0&&x1<WF)?1.f:0.f;
    const float vy0 = (y0>=0&&y0<HF)?1.f:0.f, vy1 = (y1>=0&&y1<HF)?1.f:0.f;
    const float w00 = wy0*wx0*vy0*vx0, w01 = wy0*wx1*vy0*vx1;
    const float w10 = wy1*wx0*vy1*vx0, w11 = wy1*wx1*vy1*vx1;
    const int x0c = min(max(x0,0),WF-1), x1c = min(max(x1,0),WF-1);
    const int y0c = min(max(y0,0),HF-1), y1c = min(max(y1,0),HF-1);
    const int o00 = y0c*WF+x0c, o01 = y0c*WF+x1c, o10 = y1c*WF+x0c, o11 = y1c*WF+x1c;
    const float* p = feat + (size_t)bix[n]*NC*HW + (size_t)c0*HW;
    float* op = out + (size_t)n*NC*SS + (size_t)c0*SS + (size_t)i*S + j;
#pragma unroll
    for (int g = 0; g < 2; ++g) {
        float v00[4], v01[4], v10[4], v11[4];
        const float* pc = p + (size_t)g*4*HW;
#pragma unroll
        for (int c = 0; c < 4; ++c) { v00[c]=pc[o00]; v01[c]=pc[o01]; v10[c]=pc[o10]; v11[c]=pc[o11]; pc += HW; }
        float* oc = op + (size_t)g*4*SS;
#pragma unroll
        for (int c = 0; c < 4; ++c) { *oc = w00*v00[c]+w01*v01[c]+w10*v10[c]+w11*v11[c]; oc += SS; }
    }
}

extern "C" void kernel_launch(void* const* d_in, const int* in_sizes, int n_in,
                              void* d_out, int out_size, void* d_ws, size_t ws_size,
                              hipStream_t stream) {
    const float* feat = (const float*)d_in[0];
    const float* obb  = (const float*)d_in[1];
    const int*   bx   = (const int*)d_in[2];
    float* out = (float*)d_out;

    const int N = in_sizes[1] / 5;                    // 256
    const int B = in_sizes[0] / (NC * HW);            // 2
    const size_t tbytes = (size_t)B * NC * HW * sizeof(unsigned short);  // 4 MB

    if (ws_size >= tbytes) {
        unsigned short* featT = (unsigned short*)d_ws;
        dim3 tg(B * HF, WF / 64, 1);
        nchw_to_nhwc_bf16_kernel<<<tg, 256, 0, stream>>>(feat, featT);

        const int nwg = N * (S / ROWS);               // 4096, divisible by 8
        RotatedROIPool_kernel<<<nwg, 256, 0, stream>>>(featT, obb, bx, out, nwg / 8);
    } else {
        dim3 grid(N * 16, NC / 8, 1);
        RotatedROIPool_nchw_kernel<<<grid, 256, 0, stream>>>(feat, obb, bx, out);
    }
}

// Round 9
// 58.828 us; speedup vs baseline: 1.1702x; 1.1702x over previous
//
#include <hip/hip_runtime.h>
#include <math.h>

// Problem constants (match reference)
#define S 64
#define NC 64          // channels (C=64 -> one NHWC bf16 pixel = 128B contiguous)
#define HF 128
#define WF 128
#define HW (HF * WF)   // 16384
#define SS (S * S)     // 4096, channel stride in out
#define EXPANDF 1.25f
#define FEAT_DOWN_INV 0.125f
#define DEG2RADF 0.017453292519943295f

typedef float vfloat4 __attribute__((ext_vector_type(4)));   // clang vector: NT-store legal

__device__ __forceinline__ unsigned int f32_to_bf16_rne(float v) {
    unsigned int u = __float_as_uint(v);
    return (u + 0x7FFFu + ((u >> 16) & 1u)) >> 16;   // finite data: no NaN concern
}
__device__ __forceinline__ float bf16_bits_to_f32(unsigned int h) {
    return __uint_as_float(h << 16);
}

// ---- NCHW f32 -> NHWC bf16 transpose, LDS-tiled (both sides coalesced) ----
__global__ __launch_bounds__(256) void nchw_to_nhwc_bf16_kernel(
    const float*    __restrict__ feat,    // (B, C, HF, WF) f32
    unsigned short* __restrict__ featT)   // (B, HF, WF, C) bf16
{
    __shared__ float lds[64 * 65];
    const int bh  = blockIdx.x;           // b*HF + h
    const int b   = bh >> 7;
    const int h   = bh & (HF - 1);
    const int w0  = blockIdx.y << 6;      // 64-wide w tile
    const int tid = threadIdx.x;
    const int t4  = tid >> 6;             // 0..3
    const int t64 = tid & 63;

#pragma unroll
    for (int k = 0; k < 16; ++k) {        // read: lanes contiguous in w (256B)
        const int c = (k << 2) + t4;
        lds[t64 * 65 + c] = feat[(((size_t)b * NC + c) * HF + h) * WF + w0 + t64];
    }
    __syncthreads();
#pragma unroll
    for (int k = 0; k < 16; ++k) {        // write: lanes contiguous in c (128B)
        const int w = (k << 2) + t4;
        featT[(((size_t)b * HF + h) * WF + w0 + w) * NC + t64] =
            (unsigned short)f32_to_bf16_rne(lds[w * 65 + t64]);
    }
}

// ---- main: channel-in-lanes bf16 gather + LDS transpose (R5 structure) ----
// block = one (n, i) output row: 64 samples x 64 channels.
// NT stores keep the 262MB write stream out of L2 so featT (4MB) stays resident.
__global__ __launch_bounds__(256) void RotatedROIPool_kernel(
    const unsigned short* __restrict__ featT,  // (B, HF, WF, C) bf16
    const float*          __restrict__ obb,    // (N, 5)
    const int*            __restrict__ bix,    // (N,)
    float*                __restrict__ out,    // (N, C, S, S)
    int nwg_per_xcd)
{
    __shared__ float lds[64 * 65];    // [sample j][channel c], +1 pad

    // bijective XCD swizzle: consecutive rows of one ROI stay on one XCD (L2 reuse)
    const int bid = blockIdx.x;
    const int wg  = (bid & 7) * nwg_per_xcd + (bid >> 3);
    const int n   = wg >> 6;          // ROI
    const int i   = wg & 63;          // sample row

    const int tid  = threadIdx.x;
    const int wv   = tid >> 6;        // wave 0..3
    const int lane = tid & 63;
    const int s    = lane >> 3;       // sample-within-group 0..7
    const int c8   = lane & 7;        // channel group (8 bf16 = 16B each)

    // --- per-ROI affine ---
    const float o0 = obb[n * 5 + 0];
    const float o1 = obb[n * 5 + 1];
    const float o2 = obb[n * 5 + 2];
    const float o3 = obb[n * 5 + 3];
    const float o4 = obb[n * 5 + 4];

    const float cx  = o0 * FEAT_DOWN_INV;
    const float cy  = o1 * FEAT_DOWN_INV;
    const float wsc = o2 * FEAT_DOWN_INV * EXPANDF;
    const float hsc = o3 * FEAT_DOWN_INV * EXPANDF;
    const float th  = o4 * DEG2RADF;

    float sth, cth;
    sincosf(th, &sth, &cth);

    const float sx  = wsc * (1.0f / (float)S);
    const float sy  = hsc * (1.0f / (float)S);
    const float m00 = cth * sx;
    const float m01 = -sth * sy;
    const float m10 = EXPANDF * sx;   // replicate reference exactly (diagonal quirk)
    const float m11 = cth * sy;

    const float yg = (2.0f * (float)i + 1.0f) * (1.0f / (float)S) - 1.0f;
    const float hx = m01 * yg + cx;   // j-independent parts
    const float hy = m11 * yg + cy;

    const int b = bix[n];
    const unsigned char* __restrict__ pb =
        (const unsigned char*)featT + (size_t)b * ((size_t)HW * NC * 2);

    // --- phase 1: gather. wave covers j = wv*16 .. wv*16+15, 8 samples/iter ---
#pragma unroll
    for (int sg = 0; sg < 2; ++sg) {
        const int j = (wv << 4) + (sg << 3) + s;

        const float xg = (2.0f * (float)j + 1.0f) * (1.0f / (float)S) - 1.0f;
        const float gx = m00 * xg + hx;
        const float gy = m10 * xg + hy;

        const float ix = ((gx + 1.0f) * (float)WF - 1.0f) * 0.5f;
        const float iy = ((gy + 1.0f) * (float)HF - 1.0f) * 0.5f;

        const float x0f = floorf(ix);
        const float y0f = floorf(iy);
        const float wx1 = ix - x0f;
        const float wy1 = iy - y0f;
        const float wx0 = 1.0f - wx1;
        const float wy0 = 1.0f - wy1;

        const int x0 = (int)x0f;
        const int y0 = (int)y0f;
        const int x1 = x0 + 1;
        const int y1 = y0 + 1;

        const float vx0 = (x0 >= 0 && x0 < WF) ? 1.0f : 0.0f;
        const float vx1 = (x1 >= 0 && x1 < WF) ? 1.0f : 0.0f;
        const float vy0 = (y0 >= 0 && y0 < HF) ? 1.0f : 0.0f;
        const float vy1 = (y1 >= 0 && y1 < HF) ? 1.0f : 0.0f;

        const float w00 = wy0 * wx0 * vy0 * vx0;
        const float w01 = wy0 * wx1 * vy0 * vx1;
        const float w10 = wy1 * wx0 * vy1 * vx0;
        const float w11 = wy1 * wx1 * vy1 * vx1;

        const int x0c = min(max(x0, 0), WF - 1);
        const int x1c = min(max(x1, 0), WF - 1);
        const int y0c = min(max(y0, 0), HF - 1);
        const int y1c = min(max(y1, 0), HF - 1);

        // bf16 pixel = 128B; lane adds c8*16B -> one instr covers 8 pixels, all lines full
        const uint4 a00 = *((const uint4*)(pb + ((size_t)(y0c * WF + x0c) << 7)) + c8);
        const uint4 a01 = *((const uint4*)(pb + ((size_t)(y0c * WF + x1c) << 7)) + c8);
        const uint4 a10 = *((const uint4*)(pb + ((size_t)(y1c * WF + x0c) << 7)) + c8);
        const uint4 a11 = *((const uint4*)(pb + ((size_t)(y1c * WF + x1c) << 7)) + c8);

        const unsigned int* u00 = (const unsigned int*)&a00;
        const unsigned int* u01 = (const unsigned int*)&a01;
        const unsigned int* u10 = (const unsigned int*)&a10;
        const unsigned int* u11 = (const unsigned int*)&a11;

        // lds[j][8*c8 + m], stride 65: banks (j + 8*c8 + m)%32 -> exact 2-way (free)
        float* L = lds + j * 65 + (c8 << 3);
#pragma unroll
        for (int m = 0; m < 4; ++m) {
            const float f00l = bf16_bits_to_f32(u00[m] & 0xFFFFu);
            const float f01l = bf16_bits_to_f32(u01[m] & 0xFFFFu);
            const float f10l = bf16_bits_to_f32(u10[m] & 0xFFFFu);
            const float f11l = bf16_bits_to_f32(u11[m] & 0xFFFFu);
            const float f00h = bf16_bits_to_f32(u00[m] >> 16);
            const float f01h = bf16_bits_to_f32(u01[m] >> 16);
            const float f10h = bf16_bits_to_f32(u10[m] >> 16);
            const float f11h = bf16_bits_to_f32(u11[m] >> 16);
            L[2 * m + 0] = w00 * f00l + w01 * f01l + w10 * f10l + w11 * f11l;
            L[2 * m + 1] = w00 * f00h + w01 * f01h + w10 * f10h + w11 * f11h;
        }
    }

    __syncthreads();

    // --- phase 2: transpose out; NT stores (write-once stream, keep L2 for featT) ---
    float* __restrict__ ob = out + (size_t)n * NC * SS + (size_t)i * S;
    const int jg = tid & 15;          // j group (4 wide)
    const int cl = tid >> 4;          // 0..15
#pragma unroll
    for (int k = 0; k < 4; ++k) {
        const int c = (k << 4) + cl;
        vfloat4 t;
        t.x = lds[(jg * 4 + 0) * 65 + c];
        t.y = lds[(jg * 4 + 1) * 65 + c];
        t.z = lds[(jg * 4 + 2) * 65 + c];
        t.w = lds[(jg * 4 + 3) * 65 + c];
        // per instr: 4 channels x 256B contiguous segments = full 64B lines -> NT safe
        __builtin_nontemporal_store(t, (vfloat4*)(ob + (size_t)c * SS + (jg << 2)));
    }
}

// ---- fallback (ws too small): NCHW f32 direct gather, CT=8 ----
__global__ __launch_bounds__(256) void RotatedROIPool_nchw_kernel(
    const float* __restrict__ feat, const float* __restrict__ obb,
    const int* __restrict__ bix, float* __restrict__ out)
{
    const int tid = threadIdx.x, pid = blockIdx.x;
    const int n = pid >> 4, patch = pid & 15;
    const int pi = (patch >> 2) << 4, pj = (patch & 3) << 4;
    const int w = tid >> 6, lane = tid & 63;
    const int i = pi + ((w >> 1) << 3) + (lane >> 3);
    const int j = pj + ((w & 1) << 3) + (lane & 7);
    const int c0 = blockIdx.y * 8;

    const float cx = obb[n*5+0]*FEAT_DOWN_INV, cy = obb[n*5+1]*FEAT_DOWN_INV;
    const float wsc = obb[n*5+2]*FEAT_DOWN_INV*EXPANDF, hsc = obb[n*5+3]*FEAT_DOWN_INV*EXPANDF;
    float sth, cth; sincosf(obb[n*5+4]*DEG2RADF, &sth, &cth);
    const float sx = wsc/(float)S, sy = hsc/(float)S;
    const float m00 = cth*sx, m01 = -sth*sy, m10 = EXPANDF*sx, m11 = cth*sy;
    const float xg = (2.f*j+1.f)/(float)S - 1.f, yg = (2.f*i+1.f)/(float)S - 1.f;
    const float gx = m00*xg + m01*yg + cx, gy = m10*xg + m11*yg + cy;
    const float ix = ((gx+1.f)*WF-1.f)*.5f, iy = ((gy+1.f)*HF-1.f)*.5f;
    const float x0f = floorf(ix), y0f = floorf(iy);
    const float wx1 = ix-x0f, wy1 = iy-y0f, wx0 = 1.f-wx1, wy0 = 1.f-wy1;
    const int x0 = (int)x0f, y0 = (int)y0f, x1 = x0+1, y1 = y0+1;
    const float vx0 = (x0>=0&&x0<WF)?1.f:0.f, vx1 = (x1>=0&&x1<WF)?1.f:0.f;
    const float vy0 = (y0>=0&&y0<HF)?1.f:0.f, vy1 = (y1>=0&&y1<HF)?1.f:0.f;
    const float w00 = wy0*wx0*vy0*vx0, w01 = wy0*wx1*vy0*vx1;
    const float w10 = wy1*wx0*vy1*vx0, w11 = wy1*wx1*vy1*vx1;
    const int x0c = min(max(x0,0),WF-1), x1c = min(max(x1,0),WF-1);
    const int y0c = min(max(y0,0),HF-1), y1c = min(max(y1,0),HF-1);
    const int o00 = y0c*WF+x0c, o01 = y0c*WF+x1c, o10 = y1c*WF+x0c, o11 = y1c*WF+x1c;
    const float* p = feat + (size_t)bix[n]*NC*HW + (size_t)c0*HW;
    float* op = out + (size_t)n*NC*SS + (size_t)c0*SS + (size_t)i*S + j;
#pragma unroll
    for (int g = 0; g < 2; ++g) {
        float v00[4], v01[4], v10[4], v11[4];
        const float* pc = p + (size_t)g*4*HW;
#pragma unroll
        for (int c = 0; c < 4; ++c) { v00[c]=pc[o00]; v01[c]=pc[o01]; v10[c]=pc[o10]; v11[c]=pc[o11]; pc += HW; }
        float* oc = op + (size_t)g*4*SS;
#pragma unroll
        for (int c = 0; c < 4; ++c) { *oc = w00*v00[c]+w01*v01[c]+w10*v10[c]+w11*v11[c]; oc += SS; }
    }
}

extern "C" void kernel_launch(void* const* d_in, const int* in_sizes, int n_in,
                              void* d_out, int out_size, void* d_ws, size_t ws_size,
                              hipStream_t stream) {
    const float* feat = (const float*)d_in[0];
    const float* obb  = (const float*)d_in[1];
    const int*   bx   = (const int*)d_in[2];
    float* out = (float*)d_out;

    const int N = in_sizes[1] / 5;                    // 256
    const int B = in_sizes[0] / (NC * HW);            // 2
    const size_t tbytes = (size_t)B * NC * HW * sizeof(unsigned short);  // 4 MB

    if (ws_size >= tbytes) {
        unsigned short* featT = (unsigned short*)d_ws;
        dim3 tg(B * HF, WF / 64, 1);
        nchw_to_nhwc_bf16_kernel<<<tg, 256, 0, stream>>>(feat, featT);

        const int nwg = N * S;                        // 16384, divisible by 8
        RotatedROIPool_kernel<<<nwg, 256, 0, stream>>>(featT, obb, bx, out, nwg / 8);
    } else {
        dim3 grid(N * 16, NC / 8, 1);
        RotatedROIPool_nchw_kernel<<<grid, 256, 0, stream>>>(feat, obb, bx, out);
    }
}